// Round 12
// baseline (247.738 us; speedup 1.0000x reference)
//
#include <hip/hip_runtime.h>
#include <hip/hip_bf16.h>
#include <hip/hip_fp16.h>

// EGATConv: GATConv(heads=1) with edge features. N=40000, E=640000,
// DIN=C=128, EDIM=32, fp32 in/out.
//
// Round-17 = Round-16 resubmitted verbatim (container-failure audit found no
// in-kernel hang/OOB mechanism; R0 precedent = infra flake on resubmission).
//
// Round-16 structure (R14 + XCD-partitioned atomic counting):
//  - Atomic-floor hypothesis: 640k device-scope atomicAdd-returns pinned at
//    ~53us across R9/R11/R14 layouts with all pipes idle => suspected
//    cross-XCD cache-line migration at the coherence point.
//  - Each streamer block owns dst-range of its XCD (bid&7); 320 streamer
//    blocks per XCD cooperatively scan all 2500 edge chunks, filtering dn by
//    range => every count_p line is RMW'd from ONE XCD only.
//    Costs: eid read x8 (+20MB, trivial), ~1/8 lane divergence (latency-
//    bound phase). Rank correctness is order-independent.
//  - Grid 3200 = lcm(5,8)*80: bid%5 role split (625 GEMM + 2560 streamer),
//    exactly 4 streamers per XCD per 40-bid window -> 320 per XCD.
//  - rest identical to R14: padded count_p, erec = rank u16 | fp16 a_edge,
//    two-phase scan, no-atomic CSR edge_fill (4/thread), wave-per-node
//    gather (4-in-flight), MFMA bf16x2 GEMM, bf16 h, fp16 ex records.

#define DIN 128
#define CCH 128
#define EDIM 32
#define LDK 40  // padded k stride in ushorts (80 B rows, 16-B aligned frags)

typedef __attribute__((ext_vector_type(8))) short short8v;
typedef __attribute__((ext_vector_type(4))) float f32x4;

__device__ __forceinline__ unsigned short f2b(float v) {
    __hip_bfloat16 b = __float2bfloat16(v);
    return *(unsigned short*)&b;
}
__device__ __forceinline__ float b2f(unsigned short u) {
    return __uint_as_float((unsigned)u << 16);
}
__device__ __forceinline__ unsigned pack_bf2(float a, float b) {
    return (unsigned)f2b(a) | ((unsigned)f2b(b) << 16);
}

// ---------- fused: GEMM role (h, logits) + streamer role (count/rank/a_edge) ----------
__global__ __launch_bounds__(256, 4) void gemm_h(
    const float* __restrict__ x, const float* __restrict__ W,
    const float* __restrict__ att_src, const float* __restrict__ att_dst,
    const float* __restrict__ W_edge, const float* __restrict__ att_edge,
    const int* __restrict__ ei, const float* __restrict__ ea,
    unsigned* __restrict__ hb, float* __restrict__ a_src,
    float2* __restrict__ dinfo, unsigned* __restrict__ erec,
    int* __restrict__ count_p, int N, int E) {
    // 30720 B shared, overlaid between roles (different blocks, never both)
    __shared__ __align__(16) unsigned short smem[15360];
    unsigned short* xs_h = smem;                 // [64][LDK] x quarter hi
    unsigned short* xs_l = smem + 64 * LDK;      // lo plane
    unsigned short* wt_h = smem + 128 * LDK;     // [128][LDK] W^T quarter hi
    unsigned short* wt_l = smem + 128 * LDK + 128 * LDK;  // lo plane
    float (*vpart)[EDIM] = (float(*)[EDIM])smem;          // streamer only
    float* vl = (float*)(smem + 512);                     // byte offset 1024

    const int t = threadIdx.x;
    const int bid = blockIdx.x;
    const int g = bid / 5;
    const int r = bid % 5;

    if (r != 0) {
        // ------- streamer role: XCD-owned dst-range; atomic rank + a_edge -------
        {
            int j = t & 31, seg = t >> 5;  // 8 segments x 16 k
            const float* wr = W_edge + j * CCH + seg * 16;
            const float* ar = att_edge + seg * 16;
            float p = 0.0f;
#pragma unroll
            for (int k = 0; k < 16; ++k) p += wr[k] * ar[k];
            vpart[seg][j] = p;
        }
        __syncthreads();
        if (t < EDIM) {
            float s = 0.0f;
#pragma unroll
            for (int i = 0; i < 8; ++i) s += vpart[i][t];
            vl[t] = s;
        }
        __syncthreads();

        const int xcd = bid & 7;           // HW bid->XCD round-robin
        const int nprx = N >> 3;           // 5000 nodes per XCD partition
        const int lo = xcd * nprx;
        const int hi = lo + nprx;
        // rank among streamer blocks on this XCD (4 per 40-bid window)
        int w40 = bid / 40;
        int widx = 4 * w40;
        for (int i = w40 * 40; i < bid; ++i)
            if ((i % 5) && ((i & 7) == xcd)) ++widx;

        const int NCH = (E + 255) >> 8;    // 2500 chunks
        const int* eid = ei + E;
        const float4* ea4 = (const float4*)ea;
        const float4* vl4 = (const float4*)vl;
        for (int c = widx; c < NCH; c += 320) {
            int e = c * 256 + t;
            if (e >= E) continue;
            int dn = eid[e];
            if (dn < lo || dn >= hi) continue;  // not this XCD's dst range
            float4 q[8];
#pragma unroll
            for (int j = 0; j < 8; ++j) q[j] = ea4[(size_t)e * 8 + j];
            int rk = atomicAdd(&count_p[dn * 4], 1);
            float s = 0.0f;
#pragma unroll
            for (int j = 0; j < 8; ++j) {
                float4 v = vl4[j];  // LDS broadcast
                s += q[j].x * v.x + q[j].y * v.y + q[j].z * v.z + q[j].w * v.w;
            }
            erec[e] = (unsigned)(unsigned short)rk |
                      ((unsigned)__half_as_ushort(__float2half(s)) << 16);
        }
        return;
    }

    if (g >= N / 64) return;  // 15 spare GEMM-role blocks (grid rounding)

    // ---------------- GEMM role ----------------
    const int ln = t & 63;
    const int wv = t >> 6;
    const int lr = ln & 15;  // B col (node row) / A row (channel) in fragment
    const int lk = ln >> 4;  // k-group
    const int row0 = g * 64;

    f32x4 acc[8];
#pragma unroll
    for (int cf = 0; cf < 8; ++cf) acc[cf] = (f32x4)(0.0f);

    const float4* x4 = (const float4*)x;
    const float4* W4 = (const float4*)W;

    for (int q = 0; q < 4; ++q) {  // K quarters of 32
        __syncthreads();
        // stage x quarter: 64 rows x 32 k, fp32 -> bf16 hi/lo
#pragma unroll
        for (int i = 0; i < 2; ++i) {
            int j4 = t + 256 * i;
            int rr = j4 >> 3;
            int f4 = j4 & 7;
            float4 v = x4[(size_t)(row0 + rr) * 32 + q * 8 + f4];
            float vv[4] = {v.x, v.y, v.z, v.w};
            unsigned short h[4], l[4];
#pragma unroll
            for (int m = 0; m < 4; ++m) {
                h[m] = f2b(vv[m]);
                l[m] = f2b(vv[m] - b2f(h[m]));
            }
            uint2 uh = make_uint2((unsigned)h[0] | ((unsigned)h[1] << 16),
                                  (unsigned)h[2] | ((unsigned)h[3] << 16));
            uint2 ul = make_uint2((unsigned)l[0] | ((unsigned)l[1] << 16),
                                  (unsigned)l[2] | ((unsigned)l[3] << 16));
            *(uint2*)&xs_h[rr * LDK + f4 * 4] = uh;
            *(uint2*)&xs_l[rr * LDK + f4 * 4] = ul;
        }
        // stage W^T quarter: 32 k x 128 c, transposed to [c][k] hi/lo
        {
            int kt = t >> 5;   // k base kt*4
            int ct = t & 31;   // c base ct*4
            float w4[4][4];
#pragma unroll
            for (int i = 0; i < 4; ++i) {
                float4 v = W4[(size_t)(q * 32 + kt * 4 + i) * 32 + ct];
                w4[i][0] = v.x; w4[i][1] = v.y; w4[i][2] = v.z; w4[i][3] = v.w;
            }
#pragma unroll
            for (int cc = 0; cc < 4; ++cc) {
                unsigned short h[4], l[4];
#pragma unroll
                for (int i = 0; i < 4; ++i) {
                    h[i] = f2b(w4[i][cc]);
                    l[i] = f2b(w4[i][cc] - b2f(h[i]));
                }
                uint2 uh = make_uint2((unsigned)h[0] | ((unsigned)h[1] << 16),
                                      (unsigned)h[2] | ((unsigned)h[3] << 16));
                uint2 ul = make_uint2((unsigned)l[0] | ((unsigned)l[1] << 16),
                                      (unsigned)l[2] | ((unsigned)l[3] << 16));
                int c = ct * 4 + cc;
                *(uint2*)&wt_h[c * LDK + kt * 4] = uh;
                *(uint2*)&wt_l[c * LDK + kt * 4] = ul;
            }
        }
        __syncthreads();

        // one K=32 MFMA step per quarter
        short8v bh = *(const short8v*)&xs_h[(wv * 16 + lr) * LDK + lk * 8];
        short8v bl = *(const short8v*)&xs_l[(wv * 16 + lr) * LDK + lk * 8];
#pragma unroll
        for (int cf = 0; cf < 8; ++cf) {
            short8v ah = *(const short8v*)&wt_h[(cf * 16 + lr) * LDK + lk * 8];
            short8v al = *(const short8v*)&wt_l[(cf * 16 + lr) * LDK + lk * 8];
            acc[cf] = __builtin_amdgcn_mfma_f32_16x16x32_bf16(ah, bh, acc[cf], 0, 0, 0);
            acc[cf] = __builtin_amdgcn_mfma_f32_16x16x32_bf16(ah, bl, acc[cf], 0, 0, 0);
            acc[cf] = __builtin_amdgcn_mfma_f32_16x16x32_bf16(al, bh, acc[cf], 0, 0, 0);
        }
    }

    // outputs: lane holds h[row][c..c+3] for row=row0+wv*16+lr, c=cf*16+lk*4
    {
        const int row = row0 + wv * 16 + lr;
        float ps = 0.0f, pd = 0.0f;
#pragma unroll
        for (int cf = 0; cf < 8; ++cf) {
            int c0 = cf * 16 + lk * 4;
            float4 as4 = *(const float4*)&att_src[c0];
            float4 ad4 = *(const float4*)&att_dst[c0];
            ps += acc[cf][0] * as4.x + acc[cf][1] * as4.y +
                  acc[cf][2] * as4.z + acc[cf][3] * as4.w;
            pd += acc[cf][0] * ad4.x + acc[cf][1] * ad4.y +
                  acc[cf][2] * ad4.z + acc[cf][3] * ad4.w;
            uint2 u = make_uint2(pack_bf2(acc[cf][0], acc[cf][1]),
                                 pack_bf2(acc[cf][2], acc[cf][3]));
            *(uint2*)&hb[(size_t)row * 64 + cf * 8 + lk * 2] = u;
        }
        ps += __shfl_xor(ps, 16);
        ps += __shfl_xor(ps, 32);
        pd += __shfl_xor(pd, 16);
        pd += __shfl_xor(pd, 32);
        if (ln < 16) {
            int rw = row0 + wv * 16 + ln;
            a_src[rw] = ps;
            ((float*)&dinfo[rw])[0] = pd;  // dinfo.x = a_dst
        }
    }
}

// ---------- scan phase 1: per-block sums over padded count_p ----------
__global__ __launch_bounds__(256) void scan_part(const int* __restrict__ count_p,
                                                 int* __restrict__ bsum, int N) {
    int n = blockIdx.x * 256 + threadIdx.x;
    int s = (n < N) ? count_p[n * 4] : 0;
#pragma unroll
    for (int off = 32; off; off >>= 1) s += __shfl_down(s, off);
    __shared__ int wsum[4];
    if ((threadIdx.x & 63) == 0) wsum[threadIdx.x >> 6] = s;
    __syncthreads();
    if (threadIdx.x == 0)
        bsum[blockIdx.x] = wsum[0] + wsum[1] + wsum[2] + wsum[3];
}

// ---------- scan phase 2: exclusive offs + dinfo.y = bits(offs) ----------
__global__ __launch_bounds__(256) void scan_apply(
    const int* __restrict__ count_p, const int* __restrict__ bsum,
    int* __restrict__ offs, float2* __restrict__ dinfo, int N) {
    __shared__ int s_boff;
    __shared__ int wt[4];
    if (threadIdx.x == 0) {
        int s = 0;
        for (int i = 0; i < (int)blockIdx.x; ++i) s += bsum[i];
        s_boff = s;
    }
    int n = blockIdx.x * 256 + threadIdx.x;
    int c = (n < N) ? count_p[n * 4] : 0;
    int lane = threadIdx.x & 63, w = threadIdx.x >> 6;
    int inc = c;
#pragma unroll
    for (int off = 1; off < 64; off <<= 1) {
        int u = __shfl_up(inc, off);
        if (lane >= off) inc += u;
    }
    if (lane == 63) wt[w] = inc;
    __syncthreads();
    int woff = 0;
    for (int i = 0; i < w; ++i) woff += wt[i];
    int exd = s_boff + woff + inc - c;  // exclusive prefix
    if (n < N) {
        offs[n] = exd;
        ((int*)&dinfo[n])[1] = exd;  // dinfo.y = bits(offs)
    }
}

// ---------- edge pass: 4 edges/thread, no atomics, deterministic CSR slot ----------
__global__ __launch_bounds__(256) void edge_fill(
    const int* __restrict__ ei, const unsigned* __restrict__ erec,
    const float* __restrict__ a_src, const float2* __restrict__ dinfo,
    unsigned* __restrict__ pairs, int E) {
    const int t = threadIdx.x;
    const int base = blockIdx.x * 1024 + t;
    int eidx[4], sn[4], dn[4], rk[4];
    float ae[4];
    bool ok[4];
#pragma unroll
    for (int i = 0; i < 4; ++i) {
        eidx[i] = base + 256 * i;
        ok[i] = eidx[i] < E;
    }
#pragma unroll
    for (int i = 0; i < 4; ++i) {
        sn[i] = ok[i] ? ei[eidx[i]] : 0;
        dn[i] = ok[i] ? ei[E + eidx[i]] : 0;
    }
#pragma unroll
    for (int i = 0; i < 4; ++i) {
        unsigned er = ok[i] ? erec[eidx[i]] : 0u;
        rk[i] = (int)(er & 0xffffu);
        ae[i] = __half2float(__ushort_as_half((unsigned short)(er >> 16)));
    }
    float asv[4];
    float2 di[4];
#pragma unroll
    for (int i = 0; i < 4; ++i) {
        asv[i] = a_src[sn[i]];
        di[i] = dinfo[dn[i]];
    }
#pragma unroll
    for (int i = 0; i < 4; ++i) {
        if (!ok[i]) continue;
        float alpha = asv[i] + di[i].x + ae[i];
        alpha = alpha > 0.0f ? alpha : 0.2f * alpha;
        float ex = __expf(alpha);
        unsigned rec = (unsigned)(unsigned short)sn[i] |
                       ((unsigned)__half_as_ushort(__float2half(ex)) << 16);
        int p = __float_as_int(di[i].y) + rk[i];
        pairs[p] = rec;
    }
}

#define GATHER_EDGE(rec)                                                      \
    {                                                                         \
        unsigned q = hb[(size_t)((rec) & 0xffffu) * 64 + lane];               \
        float exv = __half2float(__ushort_as_half((unsigned short)((rec) >> 16))); \
        a0 += exv * __uint_as_float(q << 16);                                 \
        a1 += exv * __uint_as_float(q & 0xffff0000u);                         \
        sum += exv;                                                           \
    }

// ---------- gather: wave per node; out = sum(ex*h[src])/sum(ex) + bias ----------
__global__ __launch_bounds__(256) void gather_k(
    const int* __restrict__ count_p, const int* __restrict__ offs,
    const unsigned* __restrict__ pairs, const unsigned* __restrict__ hb,
    const float* __restrict__ bias, float* __restrict__ out, int N) {
    int n = blockIdx.x * 4 + (threadIdx.x >> 6);
    int lane = threadIdx.x & 63;
    if (n >= N) return;
    int cnt = count_p[n * 4];
    int start = offs[n];
    float a0 = 0.0f, a1 = 0.0f, sum = 0.0f;
    int j = 0;
    int head = (4 - (start & 3)) & 3;
    if (head > cnt) head = cnt;
    for (; j < head; ++j) {
        unsigned r = pairs[start + j];
        GATHER_EDGE(r);
    }
    int nq = (cnt - j) >> 2;
    if (nq > 0) {
        const uint4* pp4 = (const uint4*)(pairs + start + j);
        uint4 cur = pp4[0];
        for (int g = 0; g + 1 < nq; ++g) {
            uint4 nxt = pp4[g + 1];
            unsigned q0 = hb[(size_t)(cur.x & 0xffffu) * 64 + lane];
            unsigned q1 = hb[(size_t)(cur.y & 0xffffu) * 64 + lane];
            unsigned q2 = hb[(size_t)(cur.z & 0xffffu) * 64 + lane];
            unsigned q3 = hb[(size_t)(cur.w & 0xffffu) * 64 + lane];
            float e0 = __half2float(__ushort_as_half((unsigned short)(cur.x >> 16)));
            float e1 = __half2float(__ushort_as_half((unsigned short)(cur.y >> 16)));
            float e2 = __half2float(__ushort_as_half((unsigned short)(cur.z >> 16)));
            float e3 = __half2float(__ushort_as_half((unsigned short)(cur.w >> 16)));
            a0 += e0 * __uint_as_float(q0 << 16);
            a1 += e0 * __uint_as_float(q0 & 0xffff0000u);
            a0 += e1 * __uint_as_float(q1 << 16);
            a1 += e1 * __uint_as_float(q1 & 0xffff0000u);
            a0 += e2 * __uint_as_float(q2 << 16);
            a1 += e2 * __uint_as_float(q2 & 0xffff0000u);
            a0 += e3 * __uint_as_float(q3 << 16);
            a1 += e3 * __uint_as_float(q3 & 0xffff0000u);
            sum += (e0 + e1) + (e2 + e3);
            cur = nxt;
        }
        {
            unsigned q0 = hb[(size_t)(cur.x & 0xffffu) * 64 + lane];
            unsigned q1 = hb[(size_t)(cur.y & 0xffffu) * 64 + lane];
            unsigned q2 = hb[(size_t)(cur.z & 0xffffu) * 64 + lane];
            unsigned q3 = hb[(size_t)(cur.w & 0xffffu) * 64 + lane];
            float e0 = __half2float(__ushort_as_half((unsigned short)(cur.x >> 16)));
            float e1 = __half2float(__ushort_as_half((unsigned short)(cur.y >> 16)));
            float e2 = __half2float(__ushort_as_half((unsigned short)(cur.z >> 16)));
            float e3 = __half2float(__ushort_as_half((unsigned short)(cur.w >> 16)));
            a0 += e0 * __uint_as_float(q0 << 16);
            a1 += e0 * __uint_as_float(q0 & 0xffff0000u);
            a0 += e1 * __uint_as_float(q1 << 16);
            a1 += e1 * __uint_as_float(q1 & 0xffff0000u);
            a0 += e2 * __uint_as_float(q2 << 16);
            a1 += e2 * __uint_as_float(q2 & 0xffff0000u);
            a0 += e3 * __uint_as_float(q3 << 16);
            a1 += e3 * __uint_as_float(q3 & 0xffff0000u);
            sum += (e0 + e1) + (e2 + e3);
        }
        j += nq * 4;
    }
    for (; j < cnt; ++j) {
        unsigned r = pairs[start + j];
        GATHER_EDGE(r);
    }
    float inv = 1.0f / (sum + 1e-16f);
    float2 bv = *(const float2*)&bias[2 * lane];
    float2 o;
    o.x = a0 * inv + bv.x;
    o.y = a1 * inv + bv.y;
    *(float2*)&out[(size_t)n * CCH + 2 * lane] = o;
}

extern "C" void kernel_launch(void* const* d_in, const int* in_sizes, int n_in,
                              void* d_out, int out_size, void* d_ws, size_t ws_size,
                              hipStream_t stream) {
    const float* x        = (const float*)d_in[0];
    const int*   ei       = (const int*)d_in[1];
    const float* ea       = (const float*)d_in[2];
    const float* W        = (const float*)d_in[3];
    const float* W_edge   = (const float*)d_in[4];
    const float* att_src  = (const float*)d_in[5];
    const float* att_dst  = (const float*)d_in[6];
    const float* att_edge = (const float*)d_in[7];
    const float* bias     = (const float*)d_in[8];
    float* out = (float*)d_out;

    const int N = in_sizes[0] / DIN;   // 40000
    const int E = in_sizes[2] / EDIM;  // 640000
    const int NB = (N + 255) / 256;    // 157 scan blocks

    // workspace layout — ~16.64 MB, 16-B aligned segments
    char* ws = (char*)d_ws;
    unsigned* hb    = (unsigned*)ws;                          // N*64 u32  10.24MB
    unsigned* pairs = (unsigned*)(ws + (size_t)N * 64 * 4);   // E u32      2.56MB
    unsigned* erec  = pairs + E;                              // E u32      2.56MB
    float2* dinfo   = (float2*)(erec + E);                    // N float2   0.32MB
    int*    count_p = (int*)(dinfo + N);                      // N*4 i      0.64MB
    int*    offs    = count_p + N * 4;                        // N i        0.16MB
    float*  a_src   = (float*)(offs + N);                     // N f        0.16MB
    int*    bsum    = (int*)(a_src + N);                      // NB i

    hipMemsetAsync(count_p, 0, (size_t)N * 16, stream);

    gemm_h<<<3200, 256, 0, stream>>>(x, W, att_src, att_dst, W_edge,
                                     att_edge, ei, ea, hb, a_src,
                                     dinfo, erec, count_p, N, E);
    scan_part<<<NB, 256, 0, stream>>>(count_p, bsum, N);
    scan_apply<<<NB, 256, 0, stream>>>(count_p, bsum, offs, dinfo, N);
    edge_fill<<<(E + 1023) / 1024, 256, 0, stream>>>(ei, erec, a_src, dinfo,
                                                     pairs, E);
    gather_k<<<(N + 3) / 4, 256, 0, stream>>>(count_p, offs, pairs, hb, bias, out, N);
}

// Round 13
// 223.062 us; speedup vs baseline: 1.1106x; 1.1106x over previous
//
#include <hip/hip_runtime.h>
#include <hip/hip_bf16.h>
#include <hip/hip_fp16.h>

// EGATConv: GATConv(heads=1) with edge features. N=40000, E=640000,
// DIN=C=128, EDIM=32, fp32 in/out.
//
// Round-18 structure (R14 revert + 64B counter padding, zero ws cost):
//  - R17 post-mortem: XCD-partitioned counting REGRESSED (53->77.6us):
//    8x chunk visits + dependent dn->filter->ea chain serialized the
//    streamer. Reverted to R14's streamer (1 edge/thread, bid%5).
//  - THIS ROUND'S single variable: count_p padded 16B -> 64B (1 counter
//    per cache line; 64 -> 16 atomic RMWs per line). Free: count_p
//    (40000x64B = 2.56MB) ALIASES the pairs buffer -- count_p is dead
//    after scan_apply, pairs is written only after scan_apply (stream
//    order). gather_k no longer reads count_p: cnt = offs[n+1]-offs[n]
//    via sentinel offs[N]=E. ws total drops to 16.0MB.
//  - Prior padding evidence: 4B->16B gave 64->53us. If line serialization
//    is the floor, 16B->64B should give ~42-47us; if unchanged, the
//    contention theory is conclusively refuted.
//  - rest identical to R14: erec = rank u16 | fp16 a_edge fused in
//    streamer, two-phase scan, no-atomic CSR edge_fill (4/thread),
//    wave-per-node gather (4-in-flight), MFMA bf16x2 GEMM, bf16 h,
//    fp16 ex records, LDS overlay 30.7KB.

#define DIN 128
#define CCH 128
#define EDIM 32
#define LDK 40  // padded k stride in ushorts (80 B rows, 16-B aligned frags)

typedef __attribute__((ext_vector_type(8))) short short8v;
typedef __attribute__((ext_vector_type(4))) float f32x4;

__device__ __forceinline__ unsigned short f2b(float v) {
    __hip_bfloat16 b = __float2bfloat16(v);
    return *(unsigned short*)&b;
}
__device__ __forceinline__ float b2f(unsigned short u) {
    return __uint_as_float((unsigned)u << 16);
}
__device__ __forceinline__ unsigned pack_bf2(float a, float b) {
    return (unsigned)f2b(a) | ((unsigned)f2b(b) << 16);
}

// ---------- fused: GEMM role (h, logits) + streamer role (count/rank/a_edge) ----------
__global__ __launch_bounds__(256, 4) void gemm_h(
    const float* __restrict__ x, const float* __restrict__ W,
    const float* __restrict__ att_src, const float* __restrict__ att_dst,
    const float* __restrict__ W_edge, const float* __restrict__ att_edge,
    const int* __restrict__ ei, const float* __restrict__ ea,
    unsigned* __restrict__ hb, float* __restrict__ a_src,
    float2* __restrict__ dinfo, unsigned* __restrict__ erec,
    int* __restrict__ count_p, int N, int E) {
    // 30720 B shared, overlaid between roles (different blocks, never both)
    __shared__ __align__(16) unsigned short smem[15360];
    unsigned short* xs_h = smem;                 // [64][LDK] x quarter hi
    unsigned short* xs_l = smem + 64 * LDK;      // lo plane
    unsigned short* wt_h = smem + 128 * LDK;     // [128][LDK] W^T quarter hi
    unsigned short* wt_l = smem + 128 * LDK + 128 * LDK;  // lo plane
    float (*vpart)[EDIM] = (float(*)[EDIM])smem;          // streamer only
    float* vl = (float*)(smem + 512);                     // byte offset 1024

    const int t = threadIdx.x;
    const int g = blockIdx.x / 5;
    const int r = blockIdx.x % 5;

    if (r != 0) {
        // ------- streamer role: 256 edges, 1/thread; atomic rank + a_edge -------
        {
            int j = t & 31, seg = t >> 5;  // 8 segments x 16 k
            const float* wr = W_edge + j * CCH + seg * 16;
            const float* ar = att_edge + seg * 16;
            float p = 0.0f;
#pragma unroll
            for (int k = 0; k < 16; ++k) p += wr[k] * ar[k];
            vpart[seg][j] = p;
        }
        __syncthreads();
        if (t < EDIM) {
            float s = 0.0f;
#pragma unroll
            for (int i = 0; i < 8; ++i) s += vpart[i][t];
            vl[t] = s;
        }
        __syncthreads();

        const int* eid = ei + E;
        const float4* ea4 = (const float4*)ea;
        const float4* vl4 = (const float4*)vl;
        const int sIdx = g * 4 + (r - 1);  // 0..2499
        const int e = sIdx * 256 + t;
        if (e < E) {
            // issue ea loads first; atomic overlaps their latency
            float4 q[8];
#pragma unroll
            for (int j = 0; j < 8; ++j) q[j] = ea4[(size_t)e * 8 + j];
            int dn = eid[e];
            int rk = atomicAdd(&count_p[dn * 16], 1);  // 64B-padded counter
            float s = 0.0f;
#pragma unroll
            for (int j = 0; j < 8; ++j) {
                float4 v = vl4[j];  // LDS broadcast
                s += q[j].x * v.x + q[j].y * v.y + q[j].z * v.z + q[j].w * v.w;
            }
            erec[e] = (unsigned)(unsigned short)rk |
                      ((unsigned)__half_as_ushort(__float2half(s)) << 16);
        }
        return;
    }

    // ---------------- GEMM role ----------------
    const int ln = t & 63;
    const int wv = t >> 6;
    const int lr = ln & 15;  // B col (node row) / A row (channel) in fragment
    const int lk = ln >> 4;  // k-group
    const int row0 = g * 64;

    f32x4 acc[8];
#pragma unroll
    for (int cf = 0; cf < 8; ++cf) acc[cf] = (f32x4)(0.0f);

    const float4* x4 = (const float4*)x;
    const float4* W4 = (const float4*)W;

    for (int q = 0; q < 4; ++q) {  // K quarters of 32
        __syncthreads();
        // stage x quarter: 64 rows x 32 k, fp32 -> bf16 hi/lo
#pragma unroll
        for (int i = 0; i < 2; ++i) {
            int j4 = t + 256 * i;
            int rr = j4 >> 3;
            int f4 = j4 & 7;
            float4 v = x4[(size_t)(row0 + rr) * 32 + q * 8 + f4];
            float vv[4] = {v.x, v.y, v.z, v.w};
            unsigned short h[4], l[4];
#pragma unroll
            for (int m = 0; m < 4; ++m) {
                h[m] = f2b(vv[m]);
                l[m] = f2b(vv[m] - b2f(h[m]));
            }
            uint2 uh = make_uint2((unsigned)h[0] | ((unsigned)h[1] << 16),
                                  (unsigned)h[2] | ((unsigned)h[3] << 16));
            uint2 ul = make_uint2((unsigned)l[0] | ((unsigned)l[1] << 16),
                                  (unsigned)l[2] | ((unsigned)l[3] << 16));
            *(uint2*)&xs_h[rr * LDK + f4 * 4] = uh;
            *(uint2*)&xs_l[rr * LDK + f4 * 4] = ul;
        }
        // stage W^T quarter: 32 k x 128 c, transposed to [c][k] hi/lo
        {
            int kt = t >> 5;   // k base kt*4
            int ct = t & 31;   // c base ct*4
            float w4[4][4];
#pragma unroll
            for (int i = 0; i < 4; ++i) {
                float4 v = W4[(size_t)(q * 32 + kt * 4 + i) * 32 + ct];
                w4[i][0] = v.x; w4[i][1] = v.y; w4[i][2] = v.z; w4[i][3] = v.w;
            }
#pragma unroll
            for (int cc = 0; cc < 4; ++cc) {
                unsigned short h[4], l[4];
#pragma unroll
                for (int i = 0; i < 4; ++i) {
                    h[i] = f2b(w4[i][cc]);
                    l[i] = f2b(w4[i][cc] - b2f(h[i]));
                }
                uint2 uh = make_uint2((unsigned)h[0] | ((unsigned)h[1] << 16),
                                      (unsigned)h[2] | ((unsigned)h[3] << 16));
                uint2 ul = make_uint2((unsigned)l[0] | ((unsigned)l[1] << 16),
                                      (unsigned)l[2] | ((unsigned)l[3] << 16));
                int c = ct * 4 + cc;
                *(uint2*)&wt_h[c * LDK + kt * 4] = uh;
                *(uint2*)&wt_l[c * LDK + kt * 4] = ul;
            }
        }
        __syncthreads();

        // one K=32 MFMA step per quarter
        short8v bh = *(const short8v*)&xs_h[(wv * 16 + lr) * LDK + lk * 8];
        short8v bl = *(const short8v*)&xs_l[(wv * 16 + lr) * LDK + lk * 8];
#pragma unroll
        for (int cf = 0; cf < 8; ++cf) {
            short8v ah = *(const short8v*)&wt_h[(cf * 16 + lr) * LDK + lk * 8];
            short8v al = *(const short8v*)&wt_l[(cf * 16 + lr) * LDK + lk * 8];
            acc[cf] = __builtin_amdgcn_mfma_f32_16x16x32_bf16(ah, bh, acc[cf], 0, 0, 0);
            acc[cf] = __builtin_amdgcn_mfma_f32_16x16x32_bf16(ah, bl, acc[cf], 0, 0, 0);
            acc[cf] = __builtin_amdgcn_mfma_f32_16x16x32_bf16(al, bh, acc[cf], 0, 0, 0);
        }
    }

    // outputs: lane holds h[row][c..c+3] for row=row0+wv*16+lr, c=cf*16+lk*4
    {
        const int row = row0 + wv * 16 + lr;
        float ps = 0.0f, pd = 0.0f;
#pragma unroll
        for (int cf = 0; cf < 8; ++cf) {
            int c0 = cf * 16 + lk * 4;
            float4 as4 = *(const float4*)&att_src[c0];
            float4 ad4 = *(const float4*)&att_dst[c0];
            ps += acc[cf][0] * as4.x + acc[cf][1] * as4.y +
                  acc[cf][2] * as4.z + acc[cf][3] * as4.w;
            pd += acc[cf][0] * ad4.x + acc[cf][1] * ad4.y +
                  acc[cf][2] * ad4.z + acc[cf][3] * ad4.w;
            uint2 u = make_uint2(pack_bf2(acc[cf][0], acc[cf][1]),
                                 pack_bf2(acc[cf][2], acc[cf][3]));
            *(uint2*)&hb[(size_t)row * 64 + cf * 8 + lk * 2] = u;
        }
        ps += __shfl_xor(ps, 16);
        ps += __shfl_xor(ps, 32);
        pd += __shfl_xor(pd, 16);
        pd += __shfl_xor(pd, 32);
        if (ln < 16) {
            int rw = row0 + wv * 16 + ln;
            a_src[rw] = ps;
            ((float*)&dinfo[rw])[0] = pd;  // dinfo.x = a_dst
        }
    }
}

// ---------- scan phase 1: per-block sums over 64B-padded count_p ----------
__global__ __launch_bounds__(256) void scan_part(const int* __restrict__ count_p,
                                                 int* __restrict__ bsum, int N) {
    int n = blockIdx.x * 256 + threadIdx.x;
    int s = (n < N) ? count_p[n * 16] : 0;
#pragma unroll
    for (int off = 32; off; off >>= 1) s += __shfl_down(s, off);
    __shared__ int wsum[4];
    if ((threadIdx.x & 63) == 0) wsum[threadIdx.x >> 6] = s;
    __syncthreads();
    if (threadIdx.x == 0)
        bsum[blockIdx.x] = wsum[0] + wsum[1] + wsum[2] + wsum[3];
}

// ---------- scan phase 2: exclusive offs + sentinel + dinfo.y ----------
__global__ __launch_bounds__(256) void scan_apply(
    const int* __restrict__ count_p, const int* __restrict__ bsum,
    int* __restrict__ offs, float2* __restrict__ dinfo, int N, int E) {
    __shared__ int s_boff;
    __shared__ int wt[4];
    if (threadIdx.x == 0) {
        int s = 0;
        for (int i = 0; i < (int)blockIdx.x; ++i) s += bsum[i];
        s_boff = s;
    }
    if (blockIdx.x == 0 && threadIdx.x == 0) offs[N] = E;  // sentinel
    int n = blockIdx.x * 256 + threadIdx.x;
    int c = (n < N) ? count_p[n * 16] : 0;
    int lane = threadIdx.x & 63, w = threadIdx.x >> 6;
    int inc = c;
#pragma unroll
    for (int off = 1; off < 64; off <<= 1) {
        int u = __shfl_up(inc, off);
        if (lane >= off) inc += u;
    }
    if (lane == 63) wt[w] = inc;
    __syncthreads();
    int woff = 0;
    for (int i = 0; i < w; ++i) woff += wt[i];
    int exd = s_boff + woff + inc - c;  // exclusive prefix
    if (n < N) {
        offs[n] = exd;
        ((int*)&dinfo[n])[1] = exd;  // dinfo.y = bits(offs)
    }
}

// ---------- edge pass: 4 edges/thread, no atomics, deterministic CSR slot ----------
__global__ __launch_bounds__(256) void edge_fill(
    const int* __restrict__ ei, const unsigned* __restrict__ erec,
    const float* __restrict__ a_src, const float2* __restrict__ dinfo,
    unsigned* __restrict__ pairs, int E) {
    const int t = threadIdx.x;
    const int base = blockIdx.x * 1024 + t;
    int eidx[4], sn[4], dn[4], rk[4];
    float ae[4];
    bool ok[4];
#pragma unroll
    for (int i = 0; i < 4; ++i) {
        eidx[i] = base + 256 * i;
        ok[i] = eidx[i] < E;
    }
#pragma unroll
    for (int i = 0; i < 4; ++i) {
        sn[i] = ok[i] ? ei[eidx[i]] : 0;
        dn[i] = ok[i] ? ei[E + eidx[i]] : 0;
    }
#pragma unroll
    for (int i = 0; i < 4; ++i) {
        unsigned er = ok[i] ? erec[eidx[i]] : 0u;
        rk[i] = (int)(er & 0xffffu);
        ae[i] = __half2float(__ushort_as_half((unsigned short)(er >> 16)));
    }
    float asv[4];
    float2 di[4];
#pragma unroll
    for (int i = 0; i < 4; ++i) {
        asv[i] = a_src[sn[i]];
        di[i] = dinfo[dn[i]];
    }
#pragma unroll
    for (int i = 0; i < 4; ++i) {
        if (!ok[i]) continue;
        float alpha = asv[i] + di[i].x + ae[i];
        alpha = alpha > 0.0f ? alpha : 0.2f * alpha;
        float ex = __expf(alpha);
        unsigned rec = (unsigned)(unsigned short)sn[i] |
                       ((unsigned)__half_as_ushort(__float2half(ex)) << 16);
        int p = __float_as_int(di[i].y) + rk[i];
        pairs[p] = rec;
    }
}

#define GATHER_EDGE(rec)                                                      \
    {                                                                         \
        unsigned q = hb[(size_t)((rec) & 0xffffu) * 64 + lane];               \
        float exv = __half2float(__ushort_as_half((unsigned short)((rec) >> 16))); \
        a0 += exv * __uint_as_float(q << 16);                                 \
        a1 += exv * __uint_as_float(q & 0xffff0000u);                         \
        sum += exv;                                                           \
    }

// ---------- gather: wave per node; cnt from offs-diff (no count_p) ----------
__global__ __launch_bounds__(256) void gather_k(
    const int* __restrict__ offs, const unsigned* __restrict__ pairs,
    const unsigned* __restrict__ hb, const float* __restrict__ bias,
    float* __restrict__ out, int N) {
    int n = blockIdx.x * 4 + (threadIdx.x >> 6);
    int lane = threadIdx.x & 63;
    if (n >= N) return;
    int start = offs[n];
    int cnt = offs[n + 1] - start;
    float a0 = 0.0f, a1 = 0.0f, sum = 0.0f;
    int j = 0;
    int head = (4 - (start & 3)) & 3;
    if (head > cnt) head = cnt;
    for (; j < head; ++j) {
        unsigned r = pairs[start + j];
        GATHER_EDGE(r);
    }
    int nq = (cnt - j) >> 2;
    if (nq > 0) {
        const uint4* pp4 = (const uint4*)(pairs + start + j);
        uint4 cur = pp4[0];
        for (int g = 0; g + 1 < nq; ++g) {
            uint4 nxt = pp4[g + 1];
            unsigned q0 = hb[(size_t)(cur.x & 0xffffu) * 64 + lane];
            unsigned q1 = hb[(size_t)(cur.y & 0xffffu) * 64 + lane];
            unsigned q2 = hb[(size_t)(cur.z & 0xffffu) * 64 + lane];
            unsigned q3 = hb[(size_t)(cur.w & 0xffffu) * 64 + lane];
            float e0 = __half2float(__ushort_as_half((unsigned short)(cur.x >> 16)));
            float e1 = __half2float(__ushort_as_half((unsigned short)(cur.y >> 16)));
            float e2 = __half2float(__ushort_as_half((unsigned short)(cur.z >> 16)));
            float e3 = __half2float(__ushort_as_half((unsigned short)(cur.w >> 16)));
            a0 += e0 * __uint_as_float(q0 << 16);
            a1 += e0 * __uint_as_float(q0 & 0xffff0000u);
            a0 += e1 * __uint_as_float(q1 << 16);
            a1 += e1 * __uint_as_float(q1 & 0xffff0000u);
            a0 += e2 * __uint_as_float(q2 << 16);
            a1 += e2 * __uint_as_float(q2 & 0xffff0000u);
            a0 += e3 * __uint_as_float(q3 << 16);
            a1 += e3 * __uint_as_float(q3 & 0xffff0000u);
            sum += (e0 + e1) + (e2 + e3);
            cur = nxt;
        }
        {
            unsigned q0 = hb[(size_t)(cur.x & 0xffffu) * 64 + lane];
            unsigned q1 = hb[(size_t)(cur.y & 0xffffu) * 64 + lane];
            unsigned q2 = hb[(size_t)(cur.z & 0xffffu) * 64 + lane];
            unsigned q3 = hb[(size_t)(cur.w & 0xffffu) * 64 + lane];
            float e0 = __half2float(__ushort_as_half((unsigned short)(cur.x >> 16)));
            float e1 = __half2float(__ushort_as_half((unsigned short)(cur.y >> 16)));
            float e2 = __half2float(__ushort_as_half((unsigned short)(cur.z >> 16)));
            float e3 = __half2float(__ushort_as_half((unsigned short)(cur.w >> 16)));
            a0 += e0 * __uint_as_float(q0 << 16);
            a1 += e0 * __uint_as_float(q0 & 0xffff0000u);
            a0 += e1 * __uint_as_float(q1 << 16);
            a1 += e1 * __uint_as_float(q1 & 0xffff0000u);
            a0 += e2 * __uint_as_float(q2 << 16);
            a1 += e2 * __uint_as_float(q2 & 0xffff0000u);
            a0 += e3 * __uint_as_float(q3 << 16);
            a1 += e3 * __uint_as_float(q3 & 0xffff0000u);
            sum += (e0 + e1) + (e2 + e3);
        }
        j += nq * 4;
    }
    for (; j < cnt; ++j) {
        unsigned r = pairs[start + j];
        GATHER_EDGE(r);
    }
    float inv = 1.0f / (sum + 1e-16f);
    float2 bv = *(const float2*)&bias[2 * lane];
    float2 o;
    o.x = a0 * inv + bv.x;
    o.y = a1 * inv + bv.y;
    *(float2*)&out[(size_t)n * CCH + 2 * lane] = o;
}

extern "C" void kernel_launch(void* const* d_in, const int* in_sizes, int n_in,
                              void* d_out, int out_size, void* d_ws, size_t ws_size,
                              hipStream_t stream) {
    const float* x        = (const float*)d_in[0];
    const int*   ei       = (const int*)d_in[1];
    const float* ea       = (const float*)d_in[2];
    const float* W        = (const float*)d_in[3];
    const float* W_edge   = (const float*)d_in[4];
    const float* att_src  = (const float*)d_in[5];
    const float* att_dst  = (const float*)d_in[6];
    const float* att_edge = (const float*)d_in[7];
    const float* bias     = (const float*)d_in[8];
    float* out = (float*)d_out;

    const int N = in_sizes[0] / DIN;   // 40000
    const int E = in_sizes[2] / EDIM;  // 640000
    const int NB = (N + 255) / 256;    // 157 scan blocks

    // workspace layout — 16.0 MB, 16-B aligned segments
    // count_p (N x 64B = 2.56MB) ALIASES pairs: dead after scan_apply;
    // pairs written only by edge_fill (later in stream order).
    char* ws = (char*)d_ws;
    unsigned* hb    = (unsigned*)ws;                          // N*64 u32  10.24MB
    unsigned* pairs = (unsigned*)(ws + (size_t)N * 64 * 4);   // E u32      2.56MB
    int*    count_p = (int*)pairs;                            // aliased    (2.56MB)
    unsigned* erec  = pairs + E;                              // E u32      2.56MB
    float2* dinfo   = (float2*)(erec + E);                    // N float2   0.32MB
    int*    offs    = (int*)(dinfo + N);                      // N+4 i      0.16MB
    float*  a_src   = (float*)(offs + N + 4);                 // N f        0.16MB
    int*    bsum    = (int*)(a_src + N);                      // NB i

    hipMemsetAsync(count_p, 0, (size_t)N * 64, stream);

    gemm_h<<<5 * (N / 64), 256, 0, stream>>>(x, W, att_src, att_dst, W_edge,
                                             att_edge, ei, ea, hb, a_src,
                                             dinfo, erec, count_p, N, E);
    scan_part<<<NB, 256, 0, stream>>>(count_p, bsum, N);
    scan_apply<<<NB, 256, 0, stream>>>(count_p, bsum, offs, dinfo, N, E);
    edge_fill<<<(E + 1023) / 1024, 256, 0, stream>>>(ei, erec, a_src, dinfo,
                                                     pairs, E);
    gather_k<<<(N + 3) / 4, 256, 0, stream>>>(offs, pairs, hb, bias, out, N);
}